// Round 15
// baseline (118.791 us; speedup 1.0000x reference)
//
#include <hip/hip_runtime.h>
#include <hip/hip_bf16.h>

#define S_LEN 4096
#define DMODEL 512
#define NHEADS 8
#define DK 64
#define BATCH 2
#define MROWS (BATCH * S_LEN)  // 8192

typedef __attribute__((ext_vector_type(8))) short bf16x8;
typedef __attribute__((ext_vector_type(4))) float f32x4;
typedef unsigned short ushort_t;

// single-instruction pack: low16 = bf16(a), high16 = bf16(b), RNE
__device__ __forceinline__ unsigned packbf(float a, float b) {
  unsigned r;
  asm("v_cvt_pk_bf16_f32 %0, %1, %2" : "=v"(r) : "v"(a), "v"(b));
  return r;
}

__device__ __forceinline__ unsigned short bf1(float a) {
  union { __hip_bfloat16 h; unsigned short s; } u;
  u.h = __float2bfloat16(a);
  return u.s;
}

__device__ __forceinline__ float bflo(unsigned u) { return __uint_as_float(u << 16); }
__device__ __forceinline__ float bfhi(unsigned u) { return __uint_as_float(u & 0xFFFF0000u); }

__device__ __forceinline__ float fastrcp(float x) {
  float r;
  asm("v_rcp_f32 %0, %1" : "=v"(r) : "v"(x));
  return r;
}

__device__ __forceinline__ void gll16(const void* g, void* l) {
  __builtin_amdgcn_global_load_lds(
      (const __attribute__((address_space(1))) unsigned*)g,
      (__attribute__((address_space(3))) unsigned*)l, 16, 0, 0);
}

// ---------------------------------------------------------------------------
// Prep: transpose the 4 weights fp32 (k,n) -> bf16 (n,k). 1024 blocks.
// ---------------------------------------------------------------------------
__global__ __launch_bounds__(256) void prep(
    const float* __restrict__ Wq, const float* __restrict__ Wk,
    const float* __restrict__ Wv, const float* __restrict__ Wo,
    ushort_t* __restrict__ Wcat, ushort_t* __restrict__ Wot) {
  __shared__ float T[32][33];
  const int bid = blockIdx.x;
  const int tid = threadIdx.x;
  int w = bid >> 8;
  int tile = bid & 255;
  int k0 = (tile & 15) * 32, n0 = (tile >> 4) * 32;
  const float* W = w == 0 ? Wq : (w == 1 ? Wk : (w == 2 ? Wv : Wo));
  ushort_t* out = (w == 3) ? Wot : (Wcat + (size_t)w * 512 * 512);
  const int r = tid >> 3, c4 = (tid & 7) * 4;
  float4 v = *reinterpret_cast<const float4*>(W + (size_t)(k0 + r) * 512 + n0 + c4);
  T[r][c4 + 0] = v.x; T[r][c4 + 1] = v.y; T[r][c4 + 2] = v.z; T[r][c4 + 3] = v.w;
  __syncthreads();
  uint2 o;
  o.x = packbf(T[c4 + 0][r], T[c4 + 1][r]);
  o.y = packbf(T[c4 + 2][r], T[c4 + 3][r]);
  *reinterpret_cast<uint2*>(out + (size_t)(n0 + r) * 512 + k0 + c4) = o;
}

// ---------------------------------------------------------------------------
// Fused QKV GEMM: [Q|K|V] = x[8192,512](fp32, reg-staged->bf16) @ Wcat^T + b
// Flat grid 768, XCD grouping. Q scaled by CQ. Q,K -> [B,H,S,DK];
// V -> [B,H,DK,S] with within-64-key-tile permuted s order.
// ---------------------------------------------------------------------------
__global__ __launch_bounds__(256) void gemm_qkv(
    const float* __restrict__ x, const ushort_t* __restrict__ Wcat,
    const float* __restrict__ bq, const float* __restrict__ bk,
    const float* __restrict__ bv, ushort_t* __restrict__ Qo,
    ushort_t* __restrict__ Ko, ushort_t* __restrict__ Vo, float CQ) {
  __shared__ __align__(16) ushort_t SM[4][128 * 32];  // AL=SM[0..1], BL=SM[2..3]; EP overlay
  const int tid = threadIdx.x;
  const int wid = tid >> 6;
  const int lane = tid & 63;
  const int ql = lane & 15;
  const int g = lane >> 4;
  const int wr = wid >> 1, wc = wid & 1;

  const int p = blockIdx.x;
  const int xcd = p & 7, q_ = p >> 3;
  const int mi = xcd * 8 + q_ / 12;
  const int ni = q_ % 12;
  const int m0 = mi * 128, n0 = ni * 128;
  const int region = n0 >> 9;  // 0=Q 1=K 2=V

  f32x4 acc[4][4];
#pragma unroll
  for (int i = 0; i < 4; ++i)
#pragma unroll
    for (int j = 0; j < 4; ++j) acc[i][j] = (f32x4){0.f, 0.f, 0.f, 0.f};

  auto loadA = [&](int k0, uint4 av[2]) {
#pragma unroll
    for (int i = 0; i < 2; ++i) {
      int idx = i * 256 + tid;
      int r = idx >> 2;
      int c = (idx & 3) * 8;
      const float* src = x + (size_t)(m0 + r) * 512 + k0 + c;
      float4 a = *reinterpret_cast<const float4*>(src);
      float4 b = *reinterpret_cast<const float4*>(src + 4);
      av[i].x = packbf(a.x, a.y);
      av[i].y = packbf(a.z, a.w);
      av[i].z = packbf(b.x, b.y);
      av[i].w = packbf(b.z, b.w);
    }
  };
  auto writeA = [&](int buf, uint4 av[2]) {
#pragma unroll
    for (int i = 0; i < 2; ++i) {
      int idx = i * 256 + tid;
      *reinterpret_cast<uint4*>(&SM[buf][idx * 8]) = av[i];
    }
  };
  auto stageB = [&](int k0, int buf) {
#pragma unroll
    for (int i = 0; i < 2; ++i) {
      int idx = i * 256 + tid;
      int r = idx >> 2;
      int c = (idx & 3) * 8;
      gll16(Wcat + (size_t)(n0 + r) * 512 + k0 + c, &SM[2 + buf][idx * 8]);
    }
  };

  {
    uint4 av[2];
    loadA(0, av);
    writeA(0, av);
    stageB(0, 0);
  }
  __syncthreads();

  for (int t = 0; t < 16; ++t) {
    const int buf = t & 1;
    uint4 av[2];
    if (t < 15) {
      stageB((t + 1) * 32, buf ^ 1);
      loadA((t + 1) * 32, av);
    }
    const ushort_t* ALb = &SM[buf][0];
    const ushort_t* BLb = &SM[2 + buf][0];
    bf16x8 af[4], bfr[4];
#pragma unroll
    for (int mi2 = 0; mi2 < 4; ++mi2)
      af[mi2] = *reinterpret_cast<const bf16x8*>(ALb + (wr * 64 + mi2 * 16 + ql) * 32 + g * 8);
#pragma unroll
    for (int ni2 = 0; ni2 < 4; ++ni2)
      bfr[ni2] = *reinterpret_cast<const bf16x8*>(BLb + (wc * 64 + ni2 * 16 + ql) * 32 + g * 8);
#pragma unroll
    for (int mi2 = 0; mi2 < 4; ++mi2)
#pragma unroll
      for (int ni2 = 0; ni2 < 4; ++ni2)
        acc[mi2][ni2] = __builtin_amdgcn_mfma_f32_16x16x32_bf16(af[mi2], bfr[ni2], acc[mi2][ni2], 0, 0, 0);
    if (t < 15) writeA(buf ^ 1, av);
    __syncthreads();
  }

  const float* bias = region == 0 ? bq : (region == 1 ? bk : bv);
  const float scale = region == 0 ? CQ : 1.0f;
  const int nl0 = n0 - (region << 9);

  float bvv[4];
#pragma unroll
  for (int ni2 = 0; ni2 < 4; ++ni2) bvv[ni2] = bias[nl0 + wc * 64 + ni2 * 16 + ql];

  if (region <= 1) {
    ushort_t* EP = &SM[0][0];  // 32 KB overlay
#pragma unroll
    for (int mi2 = 0; mi2 < 4; ++mi2) {
#pragma unroll
      for (int ni2 = 0; ni2 < 4; ++ni2) {
        int n = wc * 64 + ni2 * 16 + ql;
#pragma unroll
        for (int reg = 0; reg < 4; ++reg) {
          int m = wr * 64 + mi2 * 16 + 4 * g + reg;
          EP[m * 128 + n] = bf1((acc[mi2][ni2][reg] + bvv[ni2]) * scale);
        }
      }
    }
    __syncthreads();
    ushort_t* outT = region == 0 ? Qo : Ko;
    const int hb = nl0 >> 6;
#pragma unroll
    for (int j = 0; j < 8; ++j) {
      int idx = j * 256 + tid;
      int row = idx >> 4;
      int chunk = idx & 15;
      uint4 v = *reinterpret_cast<const uint4*>(&EP[row * 128 + chunk * 8]);
      int h = hb + (chunk >> 3);
      int d = (chunk & 7) * 8;
      int m = m0 + row;
      int b = m >> 12, s = m & 4095;
      *reinterpret_cast<uint4*>(&outT[(((size_t)(b * NHEADS + h) * S_LEN + s) * DK) + d]) = v;
    }
  } else {
#pragma unroll
    for (int mi2 = 0; mi2 < 4; ++mi2) {
#pragma unroll
      for (int ni2 = 0; ni2 < 4; ++ni2) {
        int nl = nl0 + wc * 64 + ni2 * 16 + ql;
        int h = nl >> 6, d = nl & 63;
        int m = m0 + wr * 64 + mi2 * 16 + 4 * g;
        int b = m >> 12, s = m & 4095;
        int k6 = s & 63;
        int pos = (k6 & 32) | (((k6 >> 2) & 3) << 3) | (((k6 >> 4) & 1) << 2);
        int sperm = (s & ~63) | pos;
        uint2 o;
        o.x = packbf(acc[mi2][ni2][0] + bvv[ni2], acc[mi2][ni2][1] + bvv[ni2]);
        o.y = packbf(acc[mi2][ni2][2] + bvv[ni2], acc[mi2][ni2][3] + bvv[ni2]);
        *reinterpret_cast<uint2*>(&Vo[(((size_t)(b * NHEADS + h) * DK + d) * S_LEN) + sperm]) = o;
      }
    }
  }
}

// ---------------------------------------------------------------------------
// Fused Wo GEMM + split-combine, 64x128 tiles, 512 blocks (2/CU), XCD-grouped.
// ---------------------------------------------------------------------------
__global__ __launch_bounds__(256) void gemm_wo_fused(
    const ushort_t* __restrict__ Opart, const float* __restrict__ Lpart,
    const ushort_t* __restrict__ Wt, const float* __restrict__ bias,
    float* __restrict__ out) {
  __shared__ ushort_t AL[2][64 * 32];
  __shared__ ushort_t BL[2][128 * 32];
  const int tid = threadIdx.x;
  const int wid = tid >> 6;
  const int lane = tid & 63;
  const int ql = lane & 15;
  const int g = lane >> 4;
  const int wr = wid >> 1, wc = wid & 1;

  const int p = blockIdx.x;
  const int L = (p & 7) * 64 + (p >> 3);
  const int m0 = (L >> 2) * 64, n0 = (L & 3) * 128;

  f32x4 acc[2][4];
#pragma unroll
  for (int i = 0; i < 2; ++i)
#pragma unroll
    for (int j = 0; j < 4; ++j) acc[i][j] = (f32x4){0.f, 0.f, 0.f, 0.f};

  const int rA = tid >> 2;
  const int c8 = (tid & 3) * 8;
  const int mrow = m0 + rA;
  const int bb = mrow >> 12;
  const int sA = mrow & 4095;
  const int bhbase = bb * 8;

  auto loadA = [&](int k0, uint4& av) {
    int kg = k0 + c8;
    int h = kg >> 6, d = kg & 63;
    int bh = bhbase + h;
    size_t off = ((size_t)bh * S_LEN + sA) * 64 + d;
    uint4 a0 = *reinterpret_cast<const uint4*>(Opart + off);
    uint4 a1 = *reinterpret_cast<const uint4*>(Opart + off + (size_t)16 * S_LEN * 64);
    float l = Lpart[(size_t)bh * S_LEN + sA] + Lpart[(size_t)(16 + bh) * S_LEN + sA];
    float inv = fastrcp(l);
    unsigned u0[4] = {a0.x, a0.y, a0.z, a0.w};
    unsigned u1[4] = {a1.x, a1.y, a1.z, a1.w};
    unsigned r[4];
#pragma unroll
    for (int j = 0; j < 4; ++j) {
      float e0 = (bflo(u0[j]) + bflo(u1[j])) * inv;
      float e1 = (bfhi(u0[j]) + bfhi(u1[j])) * inv;
      r[j] = packbf(e0, e1);
    }
    av.x = r[0]; av.y = r[1]; av.z = r[2]; av.w = r[3];
  };
  auto writeA = [&](int buf, uint4 av) {
    *reinterpret_cast<uint4*>(&AL[buf][tid * 8]) = av;
  };
  auto stageB = [&](int k0, int buf) {
#pragma unroll
    for (int i = 0; i < 2; ++i) {
      int idx = i * 256 + tid;
      int r = idx >> 2;
      int c = (idx & 3) * 8;
      gll16(Wt + (size_t)(n0 + r) * 512 + k0 + c, &BL[buf][idx * 8]);
    }
  };

  {
    uint4 av;
    loadA(0, av);
    writeA(0, av);
    stageB(0, 0);
  }
  __syncthreads();

  for (int t = 0; t < 16; ++t) {
    const int buf = t & 1;
    uint4 av;
    if (t < 15) {
      stageB((t + 1) * 32, buf ^ 1);
      loadA((t + 1) * 32, av);
    }
    const ushort_t* ALb = &AL[buf][0];
    const ushort_t* BLb = &BL[buf][0];
    bf16x8 af[2], bfr[4];
#pragma unroll
    for (int mi = 0; mi < 2; ++mi)
      af[mi] = *reinterpret_cast<const bf16x8*>(ALb + (wr * 32 + mi * 16 + ql) * 32 + g * 8);
#pragma unroll
    for (int ni = 0; ni < 4; ++ni)
      bfr[ni] = *reinterpret_cast<const bf16x8*>(BLb + (wc * 64 + ni * 16 + ql) * 32 + g * 8);
#pragma unroll
    for (int mi = 0; mi < 2; ++mi)
#pragma unroll
      for (int ni = 0; ni < 4; ++ni)
        acc[mi][ni] = __builtin_amdgcn_mfma_f32_16x16x32_bf16(af[mi], bfr[ni], acc[mi][ni], 0, 0, 0);
    if (t < 15) writeA(buf ^ 1, av);
    __syncthreads();
  }

  float bv[4];
#pragma unroll
  for (int ni = 0; ni < 4; ++ni) bv[ni] = bias[n0 + wc * 64 + ni * 16 + ql];

#pragma unroll
  for (int mi = 0; mi < 2; ++mi) {
#pragma unroll
    for (int ni = 0; ni < 4; ++ni) {
      int n = n0 + wc * 64 + ni * 16 + ql;
#pragma unroll
      for (int reg = 0; reg < 4; ++reg) {
        int m = m0 + wr * 32 + mi * 16 + 4 * g + reg;
        out[(size_t)m * 512 + n] = acc[mi][ni][reg] + bv[ni];
      }
    }
  }
}

// ---------------------------------------------------------------------------
// Plain Wo GEMM (fallback, bf16 A): out = A @ Wt^T + bias, fp32.
// ---------------------------------------------------------------------------
__global__ __launch_bounds__(256) void gemm_wo(
    const ushort_t* __restrict__ A, const ushort_t* __restrict__ Wt,
    const float* __restrict__ bias, float* __restrict__ out) {
  __shared__ ushort_t AL[2][128 * 32];
  __shared__ ushort_t BL[2][128 * 32];
  const int tid = threadIdx.x;
  const int wid = tid >> 6;
  const int lane = tid & 63;
  const int ql = lane & 15;
  const int g = lane >> 4;
  const int wr = wid >> 1, wc = wid & 1;
  const int m0 = blockIdx.x * 128, n0 = blockIdx.y * 128;

  f32x4 acc[4][4];
#pragma unroll
  for (int i = 0; i < 4; ++i)
#pragma unroll
    for (int j = 0; j < 4; ++j) acc[i][j] = (f32x4){0.f, 0.f, 0.f, 0.f};

  auto stage = [&](int k0, int buf) {
#pragma unroll
    for (int i = 0; i < 2; ++i) {
      int idx = i * 256 + tid;
      int r = idx >> 2;
      int c = (idx & 3) * 8;
      gll16(A + (size_t)(m0 + r) * 512 + k0 + c, &AL[buf][idx * 8]);
      gll16(Wt + (size_t)(n0 + r) * 512 + k0 + c, &BL[buf][idx * 8]);
    }
  };

  stage(0, 0);
  __syncthreads();
  int buf = 0;

  for (int t = 0; t < 16; ++t) {
    if (t < 15) stage((t + 1) * 32, buf ^ 1);
    const ushort_t* ALb = &AL[buf][0];
    const ushort_t* BLb = &BL[buf][0];
    bf16x8 af[4], bfr[4];
#pragma unroll
    for (int mi = 0; mi < 4; ++mi)
      af[mi] = *reinterpret_cast<const bf16x8*>(ALb + (wr * 64 + mi * 16 + ql) * 32 + g * 8);
#pragma unroll
    for (int ni = 0; ni < 4; ++ni)
      bfr[ni] = *reinterpret_cast<const bf16x8*>(BLb + (wc * 64 + ni * 16 + ql) * 32 + g * 8);
#pragma unroll
    for (int mi = 0; mi < 4; ++mi)
#pragma unroll
      for (int ni = 0; ni < 4; ++ni)
        acc[mi][ni] = __builtin_amdgcn_mfma_f32_16x16x32_bf16(af[mi], bfr[ni], acc[mi][ni], 0, 0, 0);
    __syncthreads();
    buf ^= 1;
  }

  float bv[4];
#pragma unroll
  for (int ni = 0; ni < 4; ++ni) bv[ni] = bias[n0 + wc * 64 + ni * 16 + ql];

#pragma unroll
  for (int mi = 0; mi < 4; ++mi) {
#pragma unroll
    for (int ni = 0; ni < 4; ++ni) {
      int n = n0 + wc * 64 + ni * 16 + ql;
#pragma unroll
      for (int reg = 0; reg < 4; ++reg) {
        int m = m0 + wr * 64 + mi * 16 + 4 * g + reg;
        out[(size_t)m * 512 + n] = acc[mi][ni][reg] + bv[ni];
      }
    }
  }
}

// ---------------------------------------------------------------------------
// MFMA flash attention, no-max softmax, 8 waves/block (256 q), 32 q/wave.
// 128-key tiles, ONE barrier/tile. Software-pipelined within the wave:
// QK(sub0)+QK(sub1) issued together; exp(sub1) overlaps PV(sub0) MFMAs.
// launch_bounds (512,2) — the (512,4) cap of round 14 miscompiled.
// ---------------------------------------------------------------------------
template <bool SPLIT2>
__global__ __launch_bounds__(512, 2) void attn_mfma(
    const ushort_t* __restrict__ Q, const ushort_t* __restrict__ K,
    const ushort_t* __restrict__ Vt, ushort_t* __restrict__ AO,
    ushort_t* __restrict__ Opart, float* __restrict__ Lpart) {
  // [buf][sub][64 rows x 64 cols]
  __shared__ ushort_t KL[2][2][64 * 64];
  __shared__ ushort_t VL[2][2][64 * 64];

  const int tid = threadIdx.x;
  const int wid = tid >> 6;   // 0..7
  const int lane = tid & 63;
  const int g = lane >> 4;
  const int ql = lane & 15;

  int L;
  if (SPLIT2) {
    int orig = blockIdx.x;
    L = (orig & 7) * 64 + (orig >> 3);
  } else {
    L = blockIdx.x;
  }
  const int qt = L & 15;
  const int bhsp = L >> 4;
  const int sp = SPLIT2 ? (bhsp & 1) : 0;
  const int bh = SPLIT2 ? (bhsp >> 1) : bhsp;
  const int NT = SPLIT2 ? 16 : 32;        // 128-key tiles
  const int key0 = SPLIT2 ? sp * 2048 : 0;

  const ushort_t* Qb = Q + (size_t)bh * S_LEN * DK;
  const ushort_t* Kb = K + (size_t)bh * S_LEN * DK;
  const ushort_t* Vb = Vt + (size_t)bh * DK * S_LEN;

  const int qbase = qt * 256 + wid * 32;

  bf16x8 qf[2][2];
#pragma unroll
  for (int c = 0; c < 2; ++c) {
    int q = qbase + c * 16 + ql;
#pragma unroll
    for (int t = 0; t < 2; ++t)
      qf[c][t] = *reinterpret_cast<const bf16x8*>(Qb + (size_t)q * DK + t * 32 + g * 8);
  }

  bf16x8 ones;
#pragma unroll
  for (int j = 0; j < 8; ++j) ones[j] = (short)0x3F80;

  f32x4 ot[4][2];
#pragma unroll
  for (int db = 0; db < 4; ++db)
#pragma unroll
    for (int c = 0; c < 2; ++c) ot[db][c] = (f32x4){0.f, 0.f, 0.f, 0.f};
  f32x4 lacc[2];
  lacc[0] = (f32x4){0.f, 0.f, 0.f, 0.f};
  lacc[1] = (f32x4){0.f, 0.f, 0.f, 0.f};

  const int srow = lane >> 3;
  const int schk = lane & 7;
  const int r0 = wid * 8 + srow;
  const int ssc = (schk ^ srow) << 4;

  const char* gk0 = (const char*)Kb + ((size_t)(key0 + r0)) * 128 + ssc;
  const char* gk1 = gk0 + 64 * 128;
  const char* gv0 = (const char*)Vb + (size_t)r0 * (S_LEN * 2) + (size_t)key0 * 2 + ssc;
  const char* gv1 = gv0 + 128;

  char* lkBase = (char*)&KL[0][0][0] + (wid * 8) * 128 + lane * 16;
  char* lvBase = (char*)&VL[0][0][0] + (wid * 8) * 128 + lane * 16;

  int koA[4], koB[4];
#pragma unroll
  for (int kb = 0; kb < 4; ++kb) {
    int r = kb * 16 + ql;
    koA[kb] = r * 128 + (((g) ^ (r & 7)) << 4);
    koB[kb] = r * 128 + (((g + 4) ^ (r & 7)) << 4);
  }
  int voP[2][4];
#pragma unroll
  for (int t = 0; t < 2; ++t)
#pragma unroll
    for (int db = 0; db < 4; ++db) {
      int rd = db * 16 + ql;
      voP[t][db] = rd * 128 + (((t * 4 + g) ^ (rd & 7)) << 4);
    }

  // prologue: stage 128-key tile 0 into buf0
  gll16(gk0, lkBase);           gll16(gk1, lkBase + 8192);
  gll16(gv0, lvBase);           gll16(gv1, lvBase + 8192);
  gk0 += 16384; gk1 += 16384; gv0 += 256; gv1 += 256;
  __syncthreads();

  // QK^T for one 64-key sub-tile
  auto qk = [&](const char* KB, f32x4 st[4][2]) {
    __builtin_amdgcn_s_setprio(1);
#pragma unroll
    for (int kb = 0; kb < 4; ++kb) {
      bf16x8 k0 = *reinterpret_cast<const bf16x8*>(KB + koA[kb]);
      bf16x8 k1 = *reinterpret_cast<const bf16x8*>(KB + koB[kb]);
#pragma unroll
      for (int c = 0; c < 2; ++c) {
        f32x4 z = (f32x4){0.f, 0.f, 0.f, 0.f};
        z = __builtin_amdgcn_mfma_f32_16x16x32_bf16(k0, qf[c][0], z, 0, 0, 0);
        z = __builtin_amdgcn_mfma_f32_16x16x32_bf16(k1, qf[c][1], z, 0, 0, 0);
        st[kb][c] = z;
      }
    }
    __builtin_amdgcn_s_setprio(0);
  };

  // exp of one sub-tile's scores -> packed bf16
  auto mkexp = [&](f32x4 st[4][2], unsigned pk[2][4][2]) {
#pragma unroll
    for (int c = 0; c < 2; ++c)
#pragma unroll
      for (int kb = 0; kb < 4; ++kb)
#pragma unroll
        for (int r2 = 0; r2 < 2; ++r2) {
          float pa = __builtin_amdgcn_exp2f(st[kb][c][2 * r2]);
          float pb_ = __builtin_amdgcn_exp2f(st[kb][c][2 * r2 + 1]);
          pk[c][kb][r2] = packbf(pa, pb_);
        }
  };

  // PV + l for one sub-tile
  auto pv = [&](const char* VB, unsigned pk[2][4][2]) {
    __builtin_amdgcn_s_setprio(1);
#pragma unroll
    for (int t = 0; t < 2; ++t) {
      union { unsigned u[4]; bf16x8 v; } pb0, pb1;
      pb0.u[0] = pk[0][2 * t][0];     pb0.u[1] = pk[0][2 * t][1];
      pb0.u[2] = pk[0][2 * t + 1][0]; pb0.u[3] = pk[0][2 * t + 1][1];
      pb1.u[0] = pk[1][2 * t][0];     pb1.u[1] = pk[1][2 * t][1];
      pb1.u[2] = pk[1][2 * t + 1][0]; pb1.u[3] = pk[1][2 * t + 1][1];
#pragma unroll
      for (int db = 0; db < 4; ++db) {
        bf16x8 af = *reinterpret_cast<const bf16x8*>(VB + voP[t][db]);
        ot[db][0] = __builtin_amdgcn_mfma_f32_16x16x32_bf16(af, pb0.v, ot[db][0], 0, 0, 0);
        ot[db][1] = __builtin_amdgcn_mfma_f32_16x16x32_bf16(af, pb1.v, ot[db][1], 0, 0, 0);
      }
      lacc[0] = __builtin_amdgcn_mfma_f32_16x16x32_bf16(ones, pb0.v, lacc[0], 0, 0, 0);
      lacc[1] = __builtin_amdgcn_mfma_f32_16x16x32_bf16(ones, pb1.v, lacc[1], 0, 0, 0);
    }
    __builtin_amdgcn_s_setprio(0);
  };

  // one 128-key tile, software-pipelined across its two sub-tiles
  auto body = [&](const char* KB, const char* VB, char* dk, char* dv, bool pref) {
    if (pref) {
      gll16(gk0, dk);           gll16(gk1, dk + 8192);
      gll16(gv0, dv);           gll16(gv1, dv + 8192);
      gk0 += 16384; gk1 += 16384; gv0 += 256; gv1 += 256;
    }
    f32x4 st0[4][2], st1[4][2];
    qk(KB, st0);          // MFMA
    qk(KB + 8192, st1);   // MFMA (fills pipe while exp0 runs)
    unsigned pk0[2][4][2], pk1[2][4][2];
    mkexp(st0, pk0);      // VALU overlaps QK(sub1) in flight
    pv(VB, pk0);          // MFMA
    mkexp(st1, pk1);      // VALU overlaps PV(sub0) in flight
    pv(VB + 8192, pk1);   // MFMA
    __syncthreads();
  };

  const char* KB0 = (const char*)&KL[0][0][0];
  const char* VB0 = (const char*)&VL[0][0][0];
  const char* KB1 = KB0 + 16384;
  const char* VB1 = VB0 + 16384;

  for (int it = 0; it < NT; it += 2) {
    body(KB0, VB0, lkBase + 16384, lvBase + 16384, true);
    body(KB1, VB1, lkBase, lvBase, it + 2 < NT);
  }

  if (SPLIT2) {
    ushort_t* Ob = Opart + (((size_t)sp * 16 + bh) * S_LEN) * 64;
#pragma unroll
    for (int c = 0; c < 2; ++c) {
      const int q = qbase + c * 16 + ql;
#pragma unroll
      for (int db = 0; db < 4; ++db) {
        uint2 o;
        o.x = packbf(ot[db][c][0], ot[db][c][1]);
        o.y = packbf(ot[db][c][2], ot[db][c][3]);
        *reinterpret_cast<uint2*>(Ob + (size_t)q * 64 + db * 16 + 4 * g) = o;
      }
      if (g == 0) Lpart[((size_t)sp * 16 + bh) * S_LEN + q] = lacc[c][0];
    }
  } else {
    const int b = bh >> 3, h = bh & 7;
#pragma unroll
    for (int c = 0; c < 2; ++c) {
      const int q = qbase + c * 16 + ql;
      float inv = 1.f / lacc[c][0];
#pragma unroll
      for (int db = 0; db < 4; ++db) {
        uint2 o;
        o.x = packbf(ot[db][c][0] * inv, ot[db][c][1] * inv);
        o.y = packbf(ot[db][c][2] * inv, ot[db][c][3] * inv);
        *reinterpret_cast<uint2*>(AO + ((size_t)b * S_LEN + q) * DMODEL + h * DK + db * 16 + g * 4) = o;
      }
    }
  }
}

extern "C" void kernel_launch(void* const* d_in, const int* in_sizes, int n_in,
                              void* d_out, int out_size, void* d_ws, size_t ws_size,
                              hipStream_t stream) {
  const float* x  = (const float*)d_in[0];
  const float* Wq = (const float*)d_in[1];
  const float* bq = (const float*)d_in[2];
  const float* Wk = (const float*)d_in[3];
  const float* bk = (const float*)d_in[4];
  const float* Wv = (const float*)d_in[5];
  const float* bv = (const float*)d_in[6];
  const float* Wo = (const float*)d_in[7];
  const float* bo = (const float*)d_in[8];
  float* out = (float*)d_out;

  const float CQ = 0.18033688f;  // 0.125 * log2(e)

  char* ws = (char*)d_ws;
  const size_t NBF = (size_t)MROWS * DMODEL;  // 4 Mi elements
  ushort_t* AObuf = (ushort_t*)ws;            // 8MB (fallback AO)
  ushort_t* Qbf = (ushort_t*)(ws + NBF * 2);
  ushort_t* Kbf = (ushort_t*)(ws + NBF * 4);
  ushort_t* Vtb = (ushort_t*)(ws + NBF * 6);

  const size_t OFF_WT    = NBF * 8;
  const size_t OFF_LPART = OFF_WT + 4 * 512 * 512 * 2;
  const size_t OFF_OPART = OFF_LPART + 512 * 1024;
  const size_t NEED_SPLIT = OFF_OPART + (size_t)2 * 16 * S_LEN * 64 * 2;  // bf16 partials
  const bool use_split = ws_size >= NEED_SPLIT;

  ushort_t* Wcat;
  if (use_split) {
    Wcat = (ushort_t*)(ws + OFF_WT);
  } else {
    Wcat = (ushort_t*)(ws + NBF * 10);
  }
  ushort_t* Wot = Wcat + 3 * 512 * 512;
  float* Lpart = (float*)(ws + OFF_LPART);
  ushort_t* Opart = (ushort_t*)(ws + OFF_OPART);

  prep<<<1024, 256, 0, stream>>>(Wq, Wk, Wv, Wo, Wcat, Wot);

  gemm_qkv<<<768, 256, 0, stream>>>(x, Wcat, bq, bk, bv, Qbf, Kbf, Vtb, CQ);

  if (use_split) {
    attn_mfma<true><<<512, 512, 0, stream>>>(Qbf, Kbf, Vtb, AObuf, Opart, Lpart);
    gemm_wo_fused<<<512, 256, 0, stream>>>(Opart, Lpart, Wot, bo, out);
  } else {
    attn_mfma<false><<<256, 512, 0, stream>>>(Qbf, Kbf, Vtb, AObuf, Opart, Lpart);
    dim3 gg(MROWS / 128, DMODEL / 128);
    gemm_wo<<<gg, 256, 0, stream>>>(AObuf, Wot, bo, out);
  }
}

// Round 16
// 115.450 us; speedup vs baseline: 1.0289x; 1.0289x over previous
//
#include <hip/hip_runtime.h>
#include <hip/hip_bf16.h>

#define S_LEN 4096
#define DMODEL 512
#define NHEADS 8
#define DK 64
#define BATCH 2
#define MROWS (BATCH * S_LEN)  // 8192

typedef __attribute__((ext_vector_type(8))) short bf16x8;
typedef __attribute__((ext_vector_type(4))) float f32x4;
typedef unsigned short ushort_t;

// single-instruction pack: low16 = bf16(a), high16 = bf16(b), RNE
__device__ __forceinline__ unsigned packbf(float a, float b) {
  unsigned r;
  asm("v_cvt_pk_bf16_f32 %0, %1, %2" : "=v"(r) : "v"(a), "v"(b));
  return r;
}

__device__ __forceinline__ unsigned short bf1(float a) {
  union { __hip_bfloat16 h; unsigned short s; } u;
  u.h = __float2bfloat16(a);
  return u.s;
}

__device__ __forceinline__ float bflo(unsigned u) { return __uint_as_float(u << 16); }
__device__ __forceinline__ float bfhi(unsigned u) { return __uint_as_float(u & 0xFFFF0000u); }

__device__ __forceinline__ float fastrcp(float x) {
  float r;
  asm("v_rcp_f32 %0, %1" : "=v"(r) : "v"(x));
  return r;
}

__device__ __forceinline__ void gll16(const void* g, void* l) {
  __builtin_amdgcn_global_load_lds(
      (const __attribute__((address_space(1))) unsigned*)g,
      (__attribute__((address_space(3))) unsigned*)l, 16, 0, 0);
}

// ---------------------------------------------------------------------------
// Prep: transpose the 4 weights fp32 (k,n) -> bf16 (n,k). 1024 blocks.
// ---------------------------------------------------------------------------
__global__ __launch_bounds__(256) void prep(
    const float* __restrict__ Wq, const float* __restrict__ Wk,
    const float* __restrict__ Wv, const float* __restrict__ Wo,
    ushort_t* __restrict__ Wcat, ushort_t* __restrict__ Wot) {
  __shared__ float T[32][33];
  const int bid = blockIdx.x;
  const int tid = threadIdx.x;
  int w = bid >> 8;
  int tile = bid & 255;
  int k0 = (tile & 15) * 32, n0 = (tile >> 4) * 32;
  const float* W = w == 0 ? Wq : (w == 1 ? Wk : (w == 2 ? Wv : Wo));
  ushort_t* out = (w == 3) ? Wot : (Wcat + (size_t)w * 512 * 512);
  const int r = tid >> 3, c4 = (tid & 7) * 4;
  float4 v = *reinterpret_cast<const float4*>(W + (size_t)(k0 + r) * 512 + n0 + c4);
  T[r][c4 + 0] = v.x; T[r][c4 + 1] = v.y; T[r][c4 + 2] = v.z; T[r][c4 + 3] = v.w;
  __syncthreads();
  uint2 o;
  o.x = packbf(T[c4 + 0][r], T[c4 + 1][r]);
  o.y = packbf(T[c4 + 2][r], T[c4 + 3][r]);
  *reinterpret_cast<uint2*>(out + (size_t)(n0 + r) * 512 + k0 + c4) = o;
}

// ---------------------------------------------------------------------------
// Fused QKV GEMM: [Q|K|V] = x[8192,512](fp32, reg-staged->bf16) @ Wcat^T + b
// Flat grid 768, XCD grouping. Q scaled by CQ. Q,K -> bf16 [B,H,S,DK];
// V -> [B,H,DK,S] with within-64-key-tile permuted s order.
// Epilogue: Q/K via LDS-transposed 128B-coalesced uint4 stores; V via uint2.
// ---------------------------------------------------------------------------
__global__ __launch_bounds__(256) void gemm_qkv(
    const float* __restrict__ x, const ushort_t* __restrict__ Wcat,
    const float* __restrict__ bq, const float* __restrict__ bk,
    const float* __restrict__ bv, ushort_t* __restrict__ Qo,
    ushort_t* __restrict__ Ko, ushort_t* __restrict__ Vo, float CQ) {
  __shared__ __align__(16) ushort_t SM[4][128 * 32];  // AL=SM[0..1], BL=SM[2..3]; EP overlay
  const int tid = threadIdx.x;
  const int wid = tid >> 6;
  const int lane = tid & 63;
  const int ql = lane & 15;
  const int g = lane >> 4;
  const int wr = wid >> 1, wc = wid & 1;

  const int p = blockIdx.x;
  const int xcd = p & 7, q_ = p >> 3;
  const int mi = xcd * 8 + q_ / 12;
  const int ni = q_ % 12;
  const int m0 = mi * 128, n0 = ni * 128;
  const int region = n0 >> 9;  // 0=Q 1=K 2=V

  f32x4 acc[4][4];
#pragma unroll
  for (int i = 0; i < 4; ++i)
#pragma unroll
    for (int j = 0; j < 4; ++j) acc[i][j] = (f32x4){0.f, 0.f, 0.f, 0.f};

  auto loadA = [&](int k0, uint4 av[2]) {
#pragma unroll
    for (int i = 0; i < 2; ++i) {
      int idx = i * 256 + tid;
      int r = idx >> 2;
      int c = (idx & 3) * 8;
      const float* src = x + (size_t)(m0 + r) * 512 + k0 + c;
      float4 a = *reinterpret_cast<const float4*>(src);
      float4 b = *reinterpret_cast<const float4*>(src + 4);
      av[i].x = packbf(a.x, a.y);
      av[i].y = packbf(a.z, a.w);
      av[i].z = packbf(b.x, b.y);
      av[i].w = packbf(b.z, b.w);
    }
  };
  auto writeA = [&](int buf, uint4 av[2]) {
#pragma unroll
    for (int i = 0; i < 2; ++i) {
      int idx = i * 256 + tid;
      *reinterpret_cast<uint4*>(&SM[buf][idx * 8]) = av[i];
    }
  };
  auto stageB = [&](int k0, int buf) {
#pragma unroll
    for (int i = 0; i < 2; ++i) {
      int idx = i * 256 + tid;
      int r = idx >> 2;
      int c = (idx & 3) * 8;
      gll16(Wcat + (size_t)(n0 + r) * 512 + k0 + c, &SM[2 + buf][idx * 8]);
    }
  };

  {
    uint4 av[2];
    loadA(0, av);
    writeA(0, av);
    stageB(0, 0);
  }
  __syncthreads();

  for (int t = 0; t < 16; ++t) {
    const int buf = t & 1;
    uint4 av[2];
    if (t < 15) {
      stageB((t + 1) * 32, buf ^ 1);
      loadA((t + 1) * 32, av);
    }
    const ushort_t* ALb = &SM[buf][0];
    const ushort_t* BLb = &SM[2 + buf][0];
    bf16x8 af[4], bfr[4];
#pragma unroll
    for (int mi2 = 0; mi2 < 4; ++mi2)
      af[mi2] = *reinterpret_cast<const bf16x8*>(ALb + (wr * 64 + mi2 * 16 + ql) * 32 + g * 8);
#pragma unroll
    for (int ni2 = 0; ni2 < 4; ++ni2)
      bfr[ni2] = *reinterpret_cast<const bf16x8*>(BLb + (wc * 64 + ni2 * 16 + ql) * 32 + g * 8);
#pragma unroll
    for (int mi2 = 0; mi2 < 4; ++mi2)
#pragma unroll
      for (int ni2 = 0; ni2 < 4; ++ni2)
        acc[mi2][ni2] = __builtin_amdgcn_mfma_f32_16x16x32_bf16(af[mi2], bfr[ni2], acc[mi2][ni2], 0, 0, 0);
    if (t < 15) writeA(buf ^ 1, av);
    __syncthreads();
  }

  const float* bias = region == 0 ? bq : (region == 1 ? bk : bv);
  const float scale = region == 0 ? CQ : 1.0f;
  const int nl0 = n0 - (region << 9);

  float bvv[4];
#pragma unroll
  for (int ni2 = 0; ni2 < 4; ++ni2) bvv[ni2] = bias[nl0 + wc * 64 + ni2 * 16 + ql];

  if (region <= 1) {
    // ---- Q/K: stash bf16 C-tile in LDS [128 m][128 n], read back coalesced
    ushort_t* EP = &SM[0][0];  // 32 KB overlay (staging dead after final barrier)
#pragma unroll
    for (int mi2 = 0; mi2 < 4; ++mi2) {
#pragma unroll
      for (int ni2 = 0; ni2 < 4; ++ni2) {
        int n = wc * 64 + ni2 * 16 + ql;
#pragma unroll
        for (int reg = 0; reg < 4; ++reg) {
          int m = wr * 64 + mi2 * 16 + 4 * g + reg;
          EP[m * 128 + n] = bf1((acc[mi2][ni2][reg] + bvv[ni2]) * scale);
        }
      }
    }
    __syncthreads();
    ushort_t* outT = region == 0 ? Qo : Ko;
    const int hb = nl0 >> 6;
#pragma unroll
    for (int j = 0; j < 8; ++j) {
      int idx = j * 256 + tid;
      int row = idx >> 4;
      int chunk = idx & 15;
      uint4 v = *reinterpret_cast<const uint4*>(&EP[row * 128 + chunk * 8]);
      int h = hb + (chunk >> 3);
      int d = (chunk & 7) * 8;
      int m = m0 + row;
      int b = m >> 12, s = m & 4095;
      *reinterpret_cast<uint4*>(&outT[(((size_t)(b * NHEADS + h) * S_LEN + s) * DK) + d]) = v;
    }
  } else {
    // ---- V: packed uint2 stores; pos() identity on low 2 bits
#pragma unroll
    for (int mi2 = 0; mi2 < 4; ++mi2) {
#pragma unroll
      for (int ni2 = 0; ni2 < 4; ++ni2) {
        int nl = nl0 + wc * 64 + ni2 * 16 + ql;
        int h = nl >> 6, d = nl & 63;
        int m = m0 + wr * 64 + mi2 * 16 + 4 * g;
        int b = m >> 12, s = m & 4095;
        int k6 = s & 63;
        int pos = (k6 & 32) | (((k6 >> 2) & 3) << 3) | (((k6 >> 4) & 1) << 2);
        int sperm = (s & ~63) | pos;
        uint2 o;
        o.x = packbf(acc[mi2][ni2][0] + bvv[ni2], acc[mi2][ni2][1] + bvv[ni2]);
        o.y = packbf(acc[mi2][ni2][2] + bvv[ni2], acc[mi2][ni2][3] + bvv[ni2]);
        *reinterpret_cast<uint2*>(&Vo[(((size_t)(b * NHEADS + h) * DK + d) * S_LEN) + sperm]) = o;
      }
    }
  }
}

// ---------------------------------------------------------------------------
// Fused Wo GEMM + split-combine, 64x128 tiles, 512 blocks (2/CU), XCD-grouped.
// A = (O0+O1)*rcp(l0+l1) reg-staged -> bf16 -> ds_write; B via gll16.
// ---------------------------------------------------------------------------
__global__ __launch_bounds__(256) void gemm_wo_fused(
    const ushort_t* __restrict__ Opart, const float* __restrict__ Lpart,
    const ushort_t* __restrict__ Wt, const float* __restrict__ bias,
    float* __restrict__ out) {
  __shared__ ushort_t AL[2][64 * 32];
  __shared__ ushort_t BL[2][128 * 32];
  const int tid = threadIdx.x;
  const int wid = tid >> 6;
  const int lane = tid & 63;
  const int ql = lane & 15;
  const int g = lane >> 4;
  const int wr = wid >> 1, wc = wid & 1;

  const int p = blockIdx.x;
  const int L = (p & 7) * 64 + (p >> 3);
  const int m0 = (L >> 2) * 64, n0 = (L & 3) * 128;

  f32x4 acc[2][4];
#pragma unroll
  for (int i = 0; i < 2; ++i)
#pragma unroll
    for (int j = 0; j < 4; ++j) acc[i][j] = (f32x4){0.f, 0.f, 0.f, 0.f};

  const int rA = tid >> 2;
  const int c8 = (tid & 3) * 8;
  const int mrow = m0 + rA;
  const int bb = mrow >> 12;
  const int sA = mrow & 4095;
  const int bhbase = bb * 8;

  auto loadA = [&](int k0, uint4& av) {
    int kg = k0 + c8;
    int h = kg >> 6, d = kg & 63;
    int bh = bhbase + h;
    size_t off = ((size_t)bh * S_LEN + sA) * 64 + d;
    uint4 a0 = *reinterpret_cast<const uint4*>(Opart + off);
    uint4 a1 = *reinterpret_cast<const uint4*>(Opart + off + (size_t)16 * S_LEN * 64);
    float l = Lpart[(size_t)bh * S_LEN + sA] + Lpart[(size_t)(16 + bh) * S_LEN + sA];
    float inv = fastrcp(l);
    unsigned u0[4] = {a0.x, a0.y, a0.z, a0.w};
    unsigned u1[4] = {a1.x, a1.y, a1.z, a1.w};
    unsigned r[4];
#pragma unroll
    for (int j = 0; j < 4; ++j) {
      float e0 = (bflo(u0[j]) + bflo(u1[j])) * inv;
      float e1 = (bfhi(u0[j]) + bfhi(u1[j])) * inv;
      r[j] = packbf(e0, e1);
    }
    av.x = r[0]; av.y = r[1]; av.z = r[2]; av.w = r[3];
  };
  auto writeA = [&](int buf, uint4 av) {
    *reinterpret_cast<uint4*>(&AL[buf][tid * 8]) = av;
  };
  auto stageB = [&](int k0, int buf) {
#pragma unroll
    for (int i = 0; i < 2; ++i) {
      int idx = i * 256 + tid;
      int r = idx >> 2;
      int c = (idx & 3) * 8;
      gll16(Wt + (size_t)(n0 + r) * 512 + k0 + c, &BL[buf][idx * 8]);
    }
  };

  {
    uint4 av;
    loadA(0, av);
    writeA(0, av);
    stageB(0, 0);
  }
  __syncthreads();

  for (int t = 0; t < 16; ++t) {
    const int buf = t & 1;
    uint4 av;
    if (t < 15) {
      stageB((t + 1) * 32, buf ^ 1);
      loadA((t + 1) * 32, av);
    }
    const ushort_t* ALb = &AL[buf][0];
    const ushort_t* BLb = &BL[buf][0];
    bf16x8 af[2], bfr[4];
#pragma unroll
    for (int mi = 0; mi < 2; ++mi)
      af[mi] = *reinterpret_cast<const bf16x8*>(ALb + (wr * 32 + mi * 16 + ql) * 32 + g * 8);
#pragma unroll
    for (int ni = 0; ni < 4; ++ni)
      bfr[ni] = *reinterpret_cast<const bf16x8*>(BLb + (wc * 64 + ni * 16 + ql) * 32 + g * 8);
#pragma unroll
    for (int mi = 0; mi < 2; ++mi)
#pragma unroll
      for (int ni = 0; ni < 4; ++ni)
        acc[mi][ni] = __builtin_amdgcn_mfma_f32_16x16x32_bf16(af[mi], bfr[ni], acc[mi][ni], 0, 0, 0);
    if (t < 15) writeA(buf ^ 1, av);
    __syncthreads();
  }

  float bv[4];
#pragma unroll
  for (int ni = 0; ni < 4; ++ni) bv[ni] = bias[n0 + wc * 64 + ni * 16 + ql];

#pragma unroll
  for (int mi = 0; mi < 2; ++mi) {
#pragma unroll
    for (int ni = 0; ni < 4; ++ni) {
      int n = n0 + wc * 64 + ni * 16 + ql;
#pragma unroll
      for (int reg = 0; reg < 4; ++reg) {
        int m = m0 + wr * 32 + mi * 16 + 4 * g + reg;
        out[(size_t)m * 512 + n] = acc[mi][ni][reg] + bv[ni];
      }
    }
  }
}

// ---------------------------------------------------------------------------
// Plain Wo GEMM (fallback, bf16 A): out = A @ Wt^T + bias, fp32.
// ---------------------------------------------------------------------------
__global__ __launch_bounds__(256) void gemm_wo(
    const ushort_t* __restrict__ A, const ushort_t* __restrict__ Wt,
    const float* __restrict__ bias, float* __restrict__ out) {
  __shared__ ushort_t AL[2][128 * 32];
  __shared__ ushort_t BL[2][128 * 32];
  const int tid = threadIdx.x;
  const int wid = tid >> 6;
  const int lane = tid & 63;
  const int ql = lane & 15;
  const int g = lane >> 4;
  const int wr = wid >> 1, wc = wid & 1;
  const int m0 = blockIdx.x * 128, n0 = blockIdx.y * 128;

  f32x4 acc[4][4];
#pragma unroll
  for (int i = 0; i < 4; ++i)
#pragma unroll
    for (int j = 0; j < 4; ++j) acc[i][j] = (f32x4){0.f, 0.f, 0.f, 0.f};

  auto stage = [&](int k0, int buf) {
#pragma unroll
    for (int i = 0; i < 2; ++i) {
      int idx = i * 256 + tid;
      int r = idx >> 2;
      int c = (idx & 3) * 8;
      gll16(A + (size_t)(m0 + r) * 512 + k0 + c, &AL[buf][idx * 8]);
      gll16(Wt + (size_t)(n0 + r) * 512 + k0 + c, &BL[buf][idx * 8]);
    }
  };

  stage(0, 0);
  __syncthreads();
  int buf = 0;

  for (int t = 0; t < 16; ++t) {
    if (t < 15) stage((t + 1) * 32, buf ^ 1);
    const ushort_t* ALb = &AL[buf][0];
    const ushort_t* BLb = &BL[buf][0];
    bf16x8 af[4], bfr[4];
#pragma unroll
    for (int mi = 0; mi < 4; ++mi)
      af[mi] = *reinterpret_cast<const bf16x8*>(ALb + (wr * 64 + mi * 16 + ql) * 32 + g * 8);
#pragma unroll
    for (int ni = 0; ni < 4; ++ni)
      bfr[ni] = *reinterpret_cast<const bf16x8*>(BLb + (wc * 64 + ni * 16 + ql) * 32 + g * 8);
#pragma unroll
    for (int mi = 0; mi < 4; ++mi)
#pragma unroll
      for (int ni = 0; ni < 4; ++ni)
        acc[mi][ni] = __builtin_amdgcn_mfma_f32_16x16x32_bf16(af[mi], bfr[ni], acc[mi][ni], 0, 0, 0);
    __syncthreads();
    buf ^= 1;
  }

  float bv[4];
#pragma unroll
  for (int ni = 0; ni < 4; ++ni) bv[ni] = bias[n0 + wc * 64 + ni * 16 + ql];

#pragma unroll
  for (int mi = 0; mi < 4; ++mi) {
#pragma unroll
    for (int ni = 0; ni < 4; ++ni) {
      int n = n0 + wc * 64 + ni * 16 + ql;
#pragma unroll
      for (int reg = 0; reg < 4; ++reg) {
        int m = m0 + wr * 64 + mi * 16 + 4 * g + reg;
        out[(size_t)m * 512 + n] = acc[mi][ni][reg] + bv[ni];
      }
    }
  }
}

// ---------------------------------------------------------------------------
// MFMA flash attention, no-max softmax, 8 waves/block (256 q), 32 q/wave.
// 128-key tiles as 2x 64-key sub-buffers: ONE barrier per 128 keys.
// Sequential half/half (round-13 config — the pipelined variant regressed:
// +16 VGPR, occupancy 33->20%). V pre-permuted, cvt_pk, bf16 partials.
// ---------------------------------------------------------------------------
template <bool SPLIT2>
__global__ __launch_bounds__(512, 2) void attn_mfma(
    const ushort_t* __restrict__ Q, const ushort_t* __restrict__ K,
    const ushort_t* __restrict__ Vt, ushort_t* __restrict__ AO,
    ushort_t* __restrict__ Opart, float* __restrict__ Lpart) {
  // [buf][sub][64 rows x 64 cols]
  __shared__ ushort_t KL[2][2][64 * 64];
  __shared__ ushort_t VL[2][2][64 * 64];

  const int tid = threadIdx.x;
  const int wid = tid >> 6;   // 0..7
  const int lane = tid & 63;
  const int g = lane >> 4;
  const int ql = lane & 15;

  int L;
  if (SPLIT2) {
    int orig = blockIdx.x;
    L = (orig & 7) * 64 + (orig >> 3);
  } else {
    L = blockIdx.x;
  }
  const int qt = L & 15;
  const int bhsp = L >> 4;
  const int sp = SPLIT2 ? (bhsp & 1) : 0;
  const int bh = SPLIT2 ? (bhsp >> 1) : bhsp;
  const int NT = SPLIT2 ? 16 : 32;        // 128-key tiles
  const int key0 = SPLIT2 ? sp * 2048 : 0;

  const ushort_t* Qb = Q + (size_t)bh * S_LEN * DK;
  const ushort_t* Kb = K + (size_t)bh * S_LEN * DK;
  const ushort_t* Vb = Vt + (size_t)bh * DK * S_LEN;

  const int qbase = qt * 256 + wid * 32;

  bf16x8 qf[2][2];
#pragma unroll
  for (int c = 0; c < 2; ++c) {
    int q = qbase + c * 16 + ql;
#pragma unroll
    for (int t = 0; t < 2; ++t)
      qf[c][t] = *reinterpret_cast<const bf16x8*>(Qb + (size_t)q * DK + t * 32 + g * 8);
  }

  bf16x8 ones;
#pragma unroll
  for (int j = 0; j < 8; ++j) ones[j] = (short)0x3F80;

  f32x4 ot[4][2];
#pragma unroll
  for (int db = 0; db < 4; ++db)
#pragma unroll
    for (int c = 0; c < 2; ++c) ot[db][c] = (f32x4){0.f, 0.f, 0.f, 0.f};
  f32x4 lacc[2];
  lacc[0] = (f32x4){0.f, 0.f, 0.f, 0.f};
  lacc[1] = (f32x4){0.f, 0.f, 0.f, 0.f};

  const int srow = lane >> 3;
  const int schk = lane & 7;
  const int r0 = wid * 8 + srow;
  const int ssc = (schk ^ srow) << 4;

  const char* gk0 = (const char*)Kb + ((size_t)(key0 + r0)) * 128 + ssc;
  const char* gk1 = gk0 + 64 * 128;
  const char* gv0 = (const char*)Vb + (size_t)r0 * (S_LEN * 2) + (size_t)key0 * 2 + ssc;
  const char* gv1 = gv0 + 128;

  char* lkBase = (char*)&KL[0][0][0] + (wid * 8) * 128 + lane * 16;
  char* lvBase = (char*)&VL[0][0][0] + (wid * 8) * 128 + lane * 16;

  int koA[4], koB[4];
#pragma unroll
  for (int kb = 0; kb < 4; ++kb) {
    int r = kb * 16 + ql;
    koA[kb] = r * 128 + (((g) ^ (r & 7)) << 4);
    koB[kb] = r * 128 + (((g + 4) ^ (r & 7)) << 4);
  }
  int voP[2][4];
#pragma unroll
  for (int t = 0; t < 2; ++t)
#pragma unroll
    for (int db = 0; db < 4; ++db) {
      int rd = db * 16 + ql;
      voP[t][db] = rd * 128 + (((t * 4 + g) ^ (rd & 7)) << 4);
    }

  // prologue: stage 128-key tile 0 into buf0
  gll16(gk0, lkBase);           gll16(gk1, lkBase + 8192);
  gll16(gv0, lvBase);           gll16(gv1, lvBase + 8192);
  gk0 += 16384; gk1 += 16384; gv0 += 256; gv1 += 256;
  __syncthreads();

  // one 64-key sub-tile: QK -> exp -> PV (no barrier)
  auto half = [&](const char* KB, const char* VB) {
    f32x4 st[4][2];
    __builtin_amdgcn_s_setprio(1);
#pragma unroll
    for (int kb = 0; kb < 4; ++kb) {
      bf16x8 k0 = *reinterpret_cast<const bf16x8*>(KB + koA[kb]);
      bf16x8 k1 = *reinterpret_cast<const bf16x8*>(KB + koB[kb]);
#pragma unroll
      for (int c = 0; c < 2; ++c) {
        f32x4 z = (f32x4){0.f, 0.f, 0.f, 0.f};
        z = __builtin_amdgcn_mfma_f32_16x16x32_bf16(k0, qf[c][0], z, 0, 0, 0);
        z = __builtin_amdgcn_mfma_f32_16x16x32_bf16(k1, qf[c][1], z, 0, 0, 0);
        st[kb][c] = z;
      }
    }
    __builtin_amdgcn_s_setprio(0);

    unsigned pk[2][4][2];
#pragma unroll
    for (int c = 0; c < 2; ++c)
#pragma unroll
      for (int kb = 0; kb < 4; ++kb)
#pragma unroll
        for (int r2 = 0; r2 < 2; ++r2) {
          float pa = __builtin_amdgcn_exp2f(st[kb][c][2 * r2]);
          float pb_ = __builtin_amdgcn_exp2f(st[kb][c][2 * r2 + 1]);
          pk[c][kb][r2] = packbf(pa, pb_);
        }

    __builtin_amdgcn_s_setprio(1);
#pragma unroll
    for (int t = 0; t < 2; ++t) {
      union { unsigned u[4]; bf16x8 v; } pb0, pb1;
      pb0.u[0] = pk[0][2 * t][0];     pb0.u[1] = pk[0][2 * t][1];
      pb0.u[2] = pk[0][2 * t + 1][0]; pb0.u[3] = pk[0][2 * t + 1][1];
      pb1.u[0] = pk[1][2 * t][0];     pb1.u[1] = pk[1][2 * t][1];
      pb1.u[2] = pk[1][2 * t + 1][0]; pb1.u[3] = pk[1][2 * t + 1][1];
#pragma unroll
      for (int db = 0; db < 4; ++db) {
        bf16x8 af = *reinterpret_cast<const bf16x8*>(VB + voP[t][db]);
        ot[db][0] = __builtin_amdgcn_mfma_f32_16x16x32_bf16(af, pb0.v, ot[db][0], 0, 0, 0);
        ot[db][1] = __builtin_amdgcn_mfma_f32_16x16x32_bf16(af, pb1.v, ot[db][1], 0, 0, 0);
      }
      lacc[0] = __builtin_amdgcn_mfma_f32_16x16x32_bf16(ones, pb0.v, lacc[0], 0, 0, 0);
      lacc[1] = __builtin_amdgcn_mfma_f32_16x16x32_bf16(ones, pb1.v, lacc[1], 0, 0, 0);
    }
    __builtin_amdgcn_s_setprio(0);
  };

  // one 128-key tile: prefetch next tile, both halves, ONE barrier
  auto body = [&](const char* KB, const char* VB, char* dk, char* dv, bool pref) {
    if (pref) {
      gll16(gk0, dk);           gll16(gk1, dk + 8192);
      gll16(gv0, dv);           gll16(gv1, dv + 8192);
      gk0 += 16384; gk1 += 16384; gv0 += 256; gv1 += 256;
    }
    half(KB, VB);
    half(KB + 8192, VB + 8192);
    __syncthreads();
  };

  const char* KB0 = (const char*)&KL[0][0][0];
  const char* VB0 = (const char*)&VL[0][0][0];
  const char* KB1 = KB0 + 16384;
  const char* VB1 = VB0 + 16384;

  for (int it = 0; it < NT; it += 2) {
    body(KB0, VB0, lkBase + 16384, lvBase + 16384, true);
    body(KB1, VB1, lkBase, lvBase, it + 2 < NT);
  }

  if (SPLIT2) {
    ushort_t* Ob = Opart + (((size_t)sp * 16 + bh) * S_LEN) * 64;
#pragma unroll
    for (int c = 0; c < 2; ++c) {
      const int q = qbase + c * 16 + ql;
#pragma unroll
      for (int db = 0; db < 4; ++db) {
        uint2 o;
        o.x = packbf(ot[db][c][0], ot[db][c][1]);
        o.y = packbf(ot[db][c][2], ot[db][c][3]);
        *reinterpret_cast<uint2*>(Ob + (size_t)q * 64 + db * 16 + 4 * g) = o;
      }
      if (g == 0) Lpart[((size_t)sp * 16 + bh) * S_LEN + q] = lacc[c][0];
    }
  } else {
    const int b = bh >> 3, h = bh & 7;
#pragma unroll
    for (int c = 0; c < 2; ++c) {
      const int q = qbase + c * 16 + ql;
      float inv = 1.f / lacc[c][0];
#pragma unroll
      for (int db = 0; db < 4; ++db) {
        uint2 o;
        o.x = packbf(ot[db][c][0] * inv, ot[db][c][1] * inv);
        o.y = packbf(ot[db][c][2] * inv, ot[db][c][3] * inv);
        *reinterpret_cast<uint2*>(AO + ((size_t)b * S_LEN + q) * DMODEL + h * DK + db * 16 + g * 4) = o;
      }
    }
  }
}

extern "C" void kernel_launch(void* const* d_in, const int* in_sizes, int n_in,
                              void* d_out, int out_size, void* d_ws, size_t ws_size,
                              hipStream_t stream) {
  const float* x  = (const float*)d_in[0];
  const float* Wq = (const float*)d_in[1];
  const float* bq = (const float*)d_in[2];
  const float* Wk = (const float*)d_in[3];
  const float* bk = (const float*)d_in[4];
  const float* Wv = (const float*)d_in[5];
  const float* bv = (const float*)d_in[6];
  const float* Wo = (const float*)d_in[7];
  const float* bo = (const float*)d_in[8];
  float* out = (float*)d_out;

  const float CQ = 0.18033688f;  // 0.125 * log2(e)

  char* ws = (char*)d_ws;
  const size_t NBF = (size_t)MROWS * DMODEL;  // 4 Mi elements
  ushort_t* AObuf = (ushort_t*)ws;            // 8MB (fallback AO)
  ushort_t* Qbf = (ushort_t*)(ws + NBF * 2);
  ushort_t* Kbf = (ushort_t*)(ws + NBF * 4);
  ushort_t* Vtb = (ushort_t*)(ws + NBF * 6);

  const size_t OFF_WT    = NBF * 8;
  const size_t OFF_LPART = OFF_WT + 4 * 512 * 512 * 2;
  const size_t OFF_OPART = OFF_LPART + 512 * 1024;
  const size_t NEED_SPLIT = OFF_OPART + (size_t)2 * 16 * S_LEN * 64 * 2;  // bf16 partials
  const bool use_split = ws_size >= NEED_SPLIT;

  ushort_t* Wcat;
  if (use_split) {
    Wcat = (ushort_t*)(ws + OFF_WT);
  } else {
    Wcat = (ushort_t*)(ws + NBF * 10);
  }
  ushort_t* Wot = Wcat + 3 * 512 * 512;
  float* Lpart = (float*)(ws + OFF_LPART);
  ushort_t* Opart = (ushort_t*)(ws + OFF_OPART);

  prep<<<1024, 256, 0, stream>>>(Wq, Wk, Wv, Wo, Wcat, Wot);

  gemm_qkv<<<768, 256, 0, stream>>>(x, Wcat, bq, bk, bv, Qbf, Kbf, Vtb, CQ);

  if (use_split) {
    attn_mfma<true><<<512, 512, 0, stream>>>(Qbf, Kbf, Vtb, AObuf, Opart, Lpart);
    gemm_wo_fused<<<512, 256, 0, stream>>>(Opart, Lpart, Wot, bo, out);
  } else {
    attn_mfma<false><<<256, 512, 0, stream>>>(Qbf, Kbf, Vtb, AObuf, Opart, Lpart);
    dim3 gg(MROWS / 128, DMODEL / 128);
    gemm_wo<<<gg, 256, 0, stream>>>(AObuf, Wot, bo, out);
  }
}